// Round 11
// baseline (130.905 us; speedup 1.0000x reference)
//
#include <hip/hip_runtime.h>
#include <hip/hip_bf16.h>

#define BATCH 32
#define SEQ   2048
#define DIM   64
#define KT    128
#define NIT   (SEQ / KT)   // 16
#define QTB   128          // q-rows per block (512 threads, 8 waves, 2 blocks/CU)

typedef __attribute__((ext_vector_type(8))) short bf16x8;
typedef __attribute__((ext_vector_type(4))) short bf16x4;
typedef __attribute__((ext_vector_type(4))) float fx4;
typedef __attribute__((ext_vector_type(4))) int   ix4;

static __device__ __forceinline__ short f2bf(float f) {
    __bf16 h = (__bf16)f;
    return *(short*)&h;
}
static __device__ __forceinline__ bf16x8 cvt8(fx4 a, fx4 b) {
    bf16x8 s;
    s[0] = f2bf(a[0]); s[1] = f2bf(a[1]); s[2] = f2bf(a[2]); s[3] = f2bf(a[3]);
    s[4] = f2bf(b[0]); s[5] = f2bf(b[1]); s[6] = f2bf(b[2]); s[7] = f2bf(b[3]);
    return s;
}
static __device__ __forceinline__ bf16x4 cvt4(float a, float b, float c, float d) {
    bf16x4 s; s[0] = f2bf(a); s[1] = f2bf(b); s[2] = f2bf(c); s[3] = f2bf(d);
    return s;
}

// exp2 trick: Q pre-scaled by log2(e)/sqrt(D)
#define QSCALE (0.125f * 1.44269504088896f)

// 512-thread block, 2 blocks/CU, KT=128 (16 barriers total; 512B/row mask per span).
// LDS (64 KB, double-buffered):
//   K buf b: [b*16384,+16384): [128 keys][128B], byte(col c)=2c ^ ((key&7)<<4)
//   V buf b: [32768+b*16384,+16384): four 32-key half-buffers (hb*4096), pair-rows
//            [32][128B]: d->(pr=d>>1,u=d&1), k5 (in-half) -> byte u*64+16*((k5>>2)&3)
//            +8*(k5>>4)+2*(k5&3), all ^ ((pr&7)<<4)
// Mask: round-8 optimal shape (instr = 4 rows x 256B): loader lane (rg=lane>>4,
//   cq=lane&15); 4-reg WAR half-pipeline: at iter t, ballot half0(t) [loaded during
//   t-1], reissue half1(t); after half0 compute, ballot half1(t), reissue half0(t+1).
// K/V staging: same-iter (issue top, ds_write bottom; ~5us flight), single regset.
//   V loaded ROW-wise (4x dwordx4 coalesced) and transposed in-register to the
//   V^T pair-row layout (4x b64 writes).
__global__ __launch_bounds__(512, 4)
void attn_fwd(const float* __restrict__ Qg, const float* __restrict__ Kg,
              const float* __restrict__ Vg, const int* __restrict__ Mg,
              float* __restrict__ Og)
{
    __shared__ __align__(16) char smem[65536];

    // XCD swizzle: grid 512 -> XCD x owns bids [x*64,(x+1)*64) = 4 batches
    const int bid   = (int)((blockIdx.x & 7) * 64 + (blockIdx.x >> 3));
    const int b     = bid >> 4;
    const int qbase = (bid & 15) * QTB;
    const int tid   = threadIdx.x;
    const int wave  = tid >> 6;
    const int lane  = tid & 63;
    const int l15   = lane & 15;
    const int g     = lane >> 4;

    // Q fragment (B-operand of swapped QK^T), pre-scaled
    const int qrow_g = qbase + wave * 16 + l15;
    const float* qrow = Qg + ((size_t)(b * SEQ + qrow_g) * DIM);
    bf16x8 qf[2];
#pragma unroll
    for (int h = 0; h < 2; ++h) {
        fx4 a = *(const fx4*)(qrow + h * 32 + g * 8);
        fx4 c = *(const fx4*)(qrow + h * 32 + g * 8 + 4);
        a *= QSCALE; c *= QSCALE;
        qf[h] = cvt8(a, c);
    }

    // mask loader + consumer constants (validated round 8)
    const int rg = lane >> 4, cq = lane & 15;
    const int* mload = Mg + ((size_t)(b * SEQ + qbase + wave * 16 + rg) * SEQ) + cq * 4;
    const bool srb0 = (l15 & 4) != 0;
    const bool srb1 = (l15 & 8) != 0;
    const int  mbase = (l15 & 3) * 16 + g;

    // K staging: thread (kr=tid>>2 in [0,128), kc16=tid&3): 4 fx4 loads, 2 b128 writes
    const int kr = tid >> 2, kc16 = tid & 3;
    const float* ksrc = Kg + ((size_t)(b * SEQ + kr) * DIM) + kc16 * 16;
    const int ksw2 = (kr & 7) * 16;
    const int kwofs0 = kr * 128 + ((kc16 * 32)      ^ ksw2);
    const int kwofs1 = kr * 128 + ((kc16 * 32 + 16) ^ ksw2);

    // V staging: thread (v4=(tid&15)*4, jgy=tid>>4 in [0,32)): keys 4jgy..+4,
    // cols v4..+4; 4 fx4 ROW loads; 4 b64 transposed writes
    const int v4 = (tid & 15) * 4, jgy = tid >> 4;
    const float* vsrc = Vg + ((size_t)(b * SEQ + 4 * jgy) * DIM) + v4;
    const int vhb = (jgy >> 3) * 4096;
    const int vcm = 16 * (jgy & 3) + 8 * ((jgy >> 2) & 1);
    const int prA = v4 >> 1, prB = prA + 1;
    int vw[4];
    vw[0] = vhb + prA * 128 + ((vcm)      ^ ((prA & 7) * 16));
    vw[1] = vhb + prA * 128 + ((64 + vcm) ^ ((prA & 7) * 16));
    vw[2] = vhb + prB * 128 + ((vcm)      ^ ((prB & 7) * 16));
    vw[3] = vhb + prB * 128 + ((64 + vcm) ^ ((prB & 7) * 16));

    // fragment read offsets (layouts validated rounds 3-10)
    const int ksw  = (l15 & 7) * 16;
    const int koh0 = l15 * 128 + ((16 * g)      ^ ksw);
    const int koh1 = l15 * 128 + ((16 * g + 64) ^ ksw);
    const int vrof = (l15 >> 1) * 128 + (((l15 & 1) * 64 + 16 * g) ^ ((l15 >> 1) * 16));

    fx4 acc[4] = {};
    float lsum = 0.f;

    fx4 kReg[4];
    fx4 vReg[4];
    ix4 m[4];

    // ---- prologue: tile 0 -> LDS buf0; masks half0(t=0) -> m ----
    {
#pragma unroll
        for (int j = 0; j < 4; ++j) kReg[j] = *(const fx4*)(ksrc + 4 * j);
#pragma unroll
        for (int i = 0; i < 4; ++i) vReg[i] = *(const fx4*)(vsrc + (size_t)i * DIM);
#pragma unroll
        for (int s = 0; s < 4; ++s)
            m[s] = __builtin_nontemporal_load((const ix4*)(mload + (size_t)4 * s * SEQ));
        *(bf16x8*)(smem + kwofs0) = cvt8(kReg[0], kReg[1]);
        *(bf16x8*)(smem + kwofs1) = cvt8(kReg[2], kReg[3]);
#pragma unroll
        for (int dd = 0; dd < 4; ++dd)
            *(bf16x4*)(smem + 32768 + vw[dd]) =
                cvt4(vReg[0][dd], vReg[1][dd], vReg[2][dd], vReg[3][dd]);
    }
    asm volatile("s_waitcnt lgkmcnt(0)" ::: "memory");
    __builtin_amdgcn_s_barrier();
    __builtin_amdgcn_sched_barrier(0);

#pragma unroll 2
    for (int kt = 0; kt < NIT; ++kt) {
        const int cur = kt & 1, nxt = cur ^ 1;
        const int kbc = kt * KT;
        const int kb1 = ((kt + 1) & (NIT - 1)) * KT;   // wraps at end: dead loads

        // A. issue K/V loads for tile t+1 (consumed by ds_write at H: ~5us flight)
#pragma unroll
        for (int j = 0; j < 4; ++j)
            kReg[j] = *(const fx4*)(ksrc + (size_t)kb1 * DIM + 4 * j);
#pragma unroll
        for (int i = 0; i < 4; ++i)
            vReg[i] = *(const fx4*)(vsrc + (size_t)(kb1 + i) * DIM);

        // B. ballot half0(t) -> bits0; reissue m <- half1(t)
        unsigned bits0[4];
#pragma unroll
        for (int i = 0; i < 4; ++i) {
            unsigned long long w0 = __ballot(m[0][i] != 0);
            unsigned long long w1 = __ballot(m[1][i] != 0);
            unsigned long long w2 = __ballot(m[2][i] != 0);
            unsigned long long w3 = __ballot(m[3][i] != 0);
            unsigned long long W = srb1 ? (srb0 ? w3 : w2) : (srb0 ? w1 : w0);
            bits0[i] = (unsigned)(W >> mbase);
        }
#pragma unroll
        for (int s = 0; s < 4; ++s)
            m[s] = __builtin_nontemporal_load(
                (const ix4*)(mload + (size_t)4 * s * SEQ + kbc + 64));

        const char* kB_ = smem + cur * 16384;
        const char* vB_ = smem + 32768 + cur * 16384 + vrof;

        // C. half0: QK subtiles 0-3, exp, PV (hb 0,1)
        {
            fx4 sc[4];
#pragma unroll
            for (int s = 0; s < 4; ++s) {
                bf16x8 kf0 = *(const bf16x8*)(kB_ + s * 2048 + koh0);
                bf16x8 kf1 = *(const bf16x8*)(kB_ + s * 2048 + koh1);
                fx4 t = {};
                t = __builtin_amdgcn_mfma_f32_16x16x32_bf16(kf0, qf[0], t, 0, 0, 0);
                t = __builtin_amdgcn_mfma_f32_16x16x32_bf16(kf1, qf[1], t, 0, 0, 0);
                sc[s] = t;
            }
            float p[16];
#pragma unroll
            for (int i = 0; i < 4; ++i) {
                p[0 + i]  = (bits0[i] & 1u)         ? 0.f : __builtin_amdgcn_exp2f(sc[0][i]);
                p[4 + i]  = ((bits0[i] >> 4) & 1u)  ? 0.f : __builtin_amdgcn_exp2f(sc[1][i]);
                p[8 + i]  = ((bits0[i] >> 8) & 1u)  ? 0.f : __builtin_amdgcn_exp2f(sc[2][i]);
                p[12 + i] = ((bits0[i] >> 12) & 1u) ? 0.f : __builtin_amdgcn_exp2f(sc[3][i]);
            }
            lsum += (((p[0] + p[1]) + (p[2] + p[3])) + ((p[4] + p[5]) + (p[6] + p[7])))
                  + (((p[8] + p[9]) + (p[10] + p[11])) + ((p[12] + p[13]) + (p[14] + p[15])));
            bf16x8 pf0, pf1;
#pragma unroll
            for (int j = 0; j < 8; ++j) { pf0[j] = f2bf(p[j]); pf1[j] = f2bf(p[8 + j]); }
#pragma unroll
            for (int dsub = 0; dsub < 4; ++dsub) {
                bf16x8 vf = *(const bf16x8*)(vB_ + dsub * 1024);
                acc[dsub] = __builtin_amdgcn_mfma_f32_16x16x32_bf16(vf, pf0, acc[dsub], 0, 0, 0);
            }
#pragma unroll
            for (int dsub = 0; dsub < 4; ++dsub) {
                bf16x8 vf = *(const bf16x8*)(vB_ + 4096 + dsub * 1024);
                acc[dsub] = __builtin_amdgcn_mfma_f32_16x16x32_bf16(vf, pf1, acc[dsub], 0, 0, 0);
            }
        }

        // D. ballot half1(t) -> bits1; reissue m <- half0(t+1)
        unsigned bits1[4];
#pragma unroll
        for (int i = 0; i < 4; ++i) {
            unsigned long long w0 = __ballot(m[0][i] != 0);
            unsigned long long w1 = __ballot(m[1][i] != 0);
            unsigned long long w2 = __ballot(m[2][i] != 0);
            unsigned long long w3 = __ballot(m[3][i] != 0);
            unsigned long long W = srb1 ? (srb0 ? w3 : w2) : (srb0 ? w1 : w0);
            bits1[i] = (unsigned)(W >> mbase);
        }
#pragma unroll
        for (int s = 0; s < 4; ++s)
            m[s] = __builtin_nontemporal_load(
                (const ix4*)(mload + (size_t)4 * s * SEQ + kb1));

        // E. half1: QK subtiles 4-7, exp, PV (hb 2,3)
        {
            fx4 sc[4];
#pragma unroll
            for (int s = 0; s < 4; ++s) {
                bf16x8 kf0 = *(const bf16x8*)(kB_ + (4 + s) * 2048 + koh0);
                bf16x8 kf1 = *(const bf16x8*)(kB_ + (4 + s) * 2048 + koh1);
                fx4 t = {};
                t = __builtin_amdgcn_mfma_f32_16x16x32_bf16(kf0, qf[0], t, 0, 0, 0);
                t = __builtin_amdgcn_mfma_f32_16x16x32_bf16(kf1, qf[1], t, 0, 0, 0);
                sc[s] = t;
            }
            float p[16];
#pragma unroll
            for (int i = 0; i < 4; ++i) {
                p[0 + i]  = (bits1[i] & 1u)         ? 0.f : __builtin_amdgcn_exp2f(sc[0][i]);
                p[4 + i]  = ((bits1[i] >> 4) & 1u)  ? 0.f : __builtin_amdgcn_exp2f(sc[1][i]);
                p[8 + i]  = ((bits1[i] >> 8) & 1u)  ? 0.f : __builtin_amdgcn_exp2f(sc[2][i]);
                p[12 + i] = ((bits1[i] >> 12) & 1u) ? 0.f : __builtin_amdgcn_exp2f(sc[3][i]);
            }
            lsum += (((p[0] + p[1]) + (p[2] + p[3])) + ((p[4] + p[5]) + (p[6] + p[7])))
                  + (((p[8] + p[9]) + (p[10] + p[11])) + ((p[12] + p[13]) + (p[14] + p[15])));
            bf16x8 pf0, pf1;
#pragma unroll
            for (int j = 0; j < 8; ++j) { pf0[j] = f2bf(p[j]); pf1[j] = f2bf(p[8 + j]); }
#pragma unroll
            for (int dsub = 0; dsub < 4; ++dsub) {
                bf16x8 vf = *(const bf16x8*)(vB_ + 8192 + dsub * 1024);
                acc[dsub] = __builtin_amdgcn_mfma_f32_16x16x32_bf16(vf, pf0, acc[dsub], 0, 0, 0);
            }
#pragma unroll
            for (int dsub = 0; dsub < 4; ++dsub) {
                bf16x8 vf = *(const bf16x8*)(vB_ + 12288 + dsub * 1024);
                acc[dsub] = __builtin_amdgcn_mfma_f32_16x16x32_bf16(vf, pf1, acc[dsub], 0, 0, 0);
            }
        }

        // H. ds_write tile t+1 into buf[nxt] (K/V loads ~5us old; auto-vmcnt
        //    leaves the younger half0(t+1) mask loads in flight)
        *(bf16x8*)(smem + nxt * 16384 + kwofs0) = cvt8(kReg[0], kReg[1]);
        *(bf16x8*)(smem + nxt * 16384 + kwofs1) = cvt8(kReg[2], kReg[3]);
#pragma unroll
        for (int dd = 0; dd < 4; ++dd)
            *(bf16x4*)(smem + 32768 + nxt * 16384 + vw[dd]) =
                cvt4(vReg[0][dd], vReg[1][dd], vReg[2][dd], vReg[3][dd]);

        // I. raw barrier: own-wave LDS drain only — no vmcnt drain
        asm volatile("s_waitcnt lgkmcnt(0)" ::: "memory");
        __builtin_amdgcn_s_barrier();
        __builtin_amdgcn_sched_barrier(0);
    }

    // ---- epilogue: reduce l over 4 g-replicas, normalize, store ----
    lsum += __shfl_xor(lsum, 16);
    lsum += __shfl_xor(lsum, 32);
    const float inv = lsum > 0.f ? 1.0f / lsum : 0.f;   // fully-masked row -> 0

    float* obase = Og + ((size_t)(b * SEQ + qrow_g) * DIM) + 4 * g;
#pragma unroll
    for (int dsub = 0; dsub < 4; ++dsub) {
        fx4 o = acc[dsub] * inv;
        __builtin_nontemporal_store(o, (fx4*)(obase + dsub * 16));
    }
}

extern "C" void kernel_launch(void* const* d_in, const int* in_sizes, int n_in,
                              void* d_out, int out_size, void* d_ws, size_t ws_size,
                              hipStream_t stream) {
    const float* Q = (const float*)d_in[0];
    const float* K = (const float*)d_in[1];
    const float* V = (const float*)d_in[2];
    const int*   M = (const int*)d_in[3];
    float*       O = (float*)d_out;
    dim3 grid(BATCH * (SEQ / QTB));
    attn_fwd<<<grid, 512, 0, stream>>>(Q, K, V, M, O);
}